// Round 15
// baseline (6983.109 us; speedup 1.0000x reference)
//
#include <hip/hip_runtime.h>
#include <hip/hip_bf16.h>

// CfC recurrent net. B=64,T=512,I=256,H=512,BU=1024.
// R15 = R11 (proven, 6.30ms) with the LAST unexamined critical-path
// component removed: buffer_inv sc0 at every barrier exit (3/step/wave).
//  - z1/z2/h stores: system-scope write-through (sc0 sc1, asm) + explicit
//    vmcnt(0) before the arrive-syncthreads (compiler can't track asm stores)
//  - data bursts: sc0 sc1 loads (bypass L1+L2, read the chip coherence point
//    -- the domain where sc0sc1 FLAG loads provably observe far writes with
//    NO invalidate)
//  - inv_l1 deleted everywhere.
// Barrier itself byte-identical to R11 (arrive = non-returning atomic_add,
// tid0 sc0sc1 load-poll + LDS fanout) — invariant across 6 designs.

#define Tt  512
#define Ii  256
#define Hh  512
#define BUu 1024

typedef __attribute__((ext_vector_type(8))) short bf16x8;   // 8 bf16 = 4 VGPR
typedef __attribute__((ext_vector_type(4))) float f32x4;

// ---- workspace layout (bytes) ----
#define OFF_WB1   0u         // bf16 [1024][768]
#define OFF_WB2   1572864u   // bf16 [1024][1024]
#define OFF_WHD   3670016u   // bf16 [1536][1024], row c=3*i+head (head2=wta+wtb)
#define OFF_Z1    6815744u   // bf16 [8 xcd][8][1024]  (16 KB per XCD)
#define OFF_Z2    6946816u   // bf16 [8 xcd][8][1024]
#define OFF_H     7077888u   // bf16 [8 xcd][8][512]   (8 KB per XCD)
#define OFF_FLAGS 7143424u   // per-XCD arrival counter @ 512B stride (4 KB)
#define OFF_POOL  7147520u   // uint[16] rank pools

// ---- LDS layout (dynamic) ----
#define SM_WB1 0         // 32 rows x 1536 B (K=768)
#define SM_WB2 49152     // 32 rows x 2048 B (K=1024)
#define SM_SA  114688    // 4 KB stage: S1/S2 [2][2][64][4]f32, S3 [3][64][4]f32
#define SM_XA  118784    // 2 KB: xpart acc [2][64][4] f32
#define SM_TOTAL 120832

__device__ __forceinline__ short f2bf(float f) {   // fp32 -> bf16 RNE
  unsigned u = __builtin_bit_cast(unsigned, f);
  u += 0x7FFFu + ((u >> 16) & 1u);
  return (short)(u >> 16);
}
__device__ __forceinline__ float fast_tanh(float u) {
  float e = __expf(2.0f * u);
  return (e - 1.0f) / (e + 1.0f);
}
__device__ __forceinline__ float fast_sig(float x) {
  return 1.0f / (1.0f + __expf(-x));
}
__device__ __forceinline__ float lecun_act(float u) {
  return 1.7159f * fast_tanh(0.666f * u);
}

// ---- transport: system-scope (coherence-point) loads/stores, no inv ----
__device__ __forceinline__ void burst8(const void* p, bf16x8* v) {
  asm volatile(
      "global_load_dwordx4 %0, %8, off sc0 sc1\n\t"
      "global_load_dwordx4 %1, %8, off offset:64 sc0 sc1\n\t"
      "global_load_dwordx4 %2, %8, off offset:128 sc0 sc1\n\t"
      "global_load_dwordx4 %3, %8, off offset:192 sc0 sc1\n\t"
      "global_load_dwordx4 %4, %8, off offset:256 sc0 sc1\n\t"
      "global_load_dwordx4 %5, %8, off offset:320 sc0 sc1\n\t"
      "global_load_dwordx4 %6, %8, off offset:384 sc0 sc1\n\t"
      "global_load_dwordx4 %7, %8, off offset:448 sc0 sc1\n\t"
      "s_waitcnt vmcnt(0)"
      : "=&v"(v[0]), "=&v"(v[1]), "=&v"(v[2]), "=&v"(v[3]),
        "=&v"(v[4]), "=&v"(v[5]), "=&v"(v[6]), "=&v"(v[7])
      : "v"(p));
}
__device__ __forceinline__ void burst16(const void* p, bf16x8* v) {
  asm volatile(
      "global_load_dwordx4 %0, %16, off sc0 sc1\n\t"
      "global_load_dwordx4 %1, %16, off offset:64 sc0 sc1\n\t"
      "global_load_dwordx4 %2, %16, off offset:128 sc0 sc1\n\t"
      "global_load_dwordx4 %3, %16, off offset:192 sc0 sc1\n\t"
      "global_load_dwordx4 %4, %16, off offset:256 sc0 sc1\n\t"
      "global_load_dwordx4 %5, %16, off offset:320 sc0 sc1\n\t"
      "global_load_dwordx4 %6, %16, off offset:384 sc0 sc1\n\t"
      "global_load_dwordx4 %7, %16, off offset:448 sc0 sc1\n\t"
      "global_load_dwordx4 %8, %16, off offset:512 sc0 sc1\n\t"
      "global_load_dwordx4 %9, %16, off offset:576 sc0 sc1\n\t"
      "global_load_dwordx4 %10, %16, off offset:640 sc0 sc1\n\t"
      "global_load_dwordx4 %11, %16, off offset:704 sc0 sc1\n\t"
      "global_load_dwordx4 %12, %16, off offset:768 sc0 sc1\n\t"
      "global_load_dwordx4 %13, %16, off offset:832 sc0 sc1\n\t"
      "global_load_dwordx4 %14, %16, off offset:896 sc0 sc1\n\t"
      "global_load_dwordx4 %15, %16, off offset:960 sc0 sc1\n\t"
      "s_waitcnt vmcnt(0)"
      : "=&v"(v[0]), "=&v"(v[1]), "=&v"(v[2]), "=&v"(v[3]),
        "=&v"(v[4]), "=&v"(v[5]), "=&v"(v[6]), "=&v"(v[7]),
        "=&v"(v[8]), "=&v"(v[9]), "=&v"(v[10]), "=&v"(v[11]),
        "=&v"(v[12]), "=&v"(v[13]), "=&v"(v[14]), "=&v"(v[15])
      : "v"(p));
}
// system-scope 2-byte store (write-through to the chip coherence point)
__device__ __forceinline__ void st2f(void* p, short v) {
  asm volatile("global_store_short %0, %1, off sc0 sc1"
               :: "v"(p), "v"((unsigned)(unsigned short)v) : "memory");
}
// flag observation: system-scope load (R11-proven, needs no invalidate)
__device__ __forceinline__ unsigned ldpoll(const unsigned* p) {
  unsigned r;
  asm volatile("global_load_dword %0, %1, off sc0 sc1\n\ts_waitcnt vmcnt(0)"
               : "=&v"(r) : "v"(p) : "memory");
  return r;
}

// arrive: explicit vmcnt(0) (asm stores aren't compiler-tracked) +
// syncthreads, then ONE non-returning atomic_add by tid0.
__device__ __forceinline__ void bar_arrive(unsigned* cnt, int tid) {
  asm volatile("s_waitcnt vmcnt(0)" ::: "memory");
  __syncthreads();
  if (tid == 0)
    asm volatile("global_atomic_add %0, %1, off" :: "v"(cnt), "v"(1u) : "memory");
}
// wait: tid0 load-polls the counter, publishes to LDS; all threads spin on
// LDS. NO buffer_inv — data reads are sc0sc1 (coherence-point direct).
__device__ __forceinline__ void bar_wait(unsigned* cnt, int tid, unsigned target,
                                         volatile unsigned* eph) {
  if (tid == 0) {
    for (int spin = 0; spin < (1 << 17); ++spin) {
      if (ldpoll(cnt) >= target) break;
      __builtin_amdgcn_s_sleep(1);
    }
    *eph = target;    // release the wg (LDS)
  }
  while (*eph < target) __builtin_amdgcn_s_sleep(1);
}

// ---- prep: weight conversion, fused head matrix, zero h/counters/pools ----
__global__ void cfc_prep(const float* __restrict__ wb1, const float* __restrict__ wb2,
                         const float* __restrict__ wff1, const float* __restrict__ wff2,
                         const float* __restrict__ wta, const float* __restrict__ wtb,
                         unsigned char* __restrict__ ws) {
  const unsigned N1 = 1024u * 768u;
  const unsigned N2 = 1024u * 1024u;
  const unsigned N3 = 1536u * 1024u;
  const unsigned NH = 32768u;          // h shorts (8 XCD x 8 x 512)
  const unsigned NF = 1040u;           // counter region 4KB + pools 64B dwords
  unsigned idx = blockIdx.x * blockDim.x + threadIdx.x;
  short* Wb1 = (short*)(ws + OFF_WB1);
  short* Wb2 = (short*)(ws + OFF_WB2);
  short* Whd = (short*)(ws + OFF_WHD);
  short* Hbuf = (short*)(ws + OFF_H);
  unsigned* flags = (unsigned*)(ws + OFF_FLAGS);
  if (idx < N1) { Wb1[idx] = f2bf(wb1[idx]); return; }
  idx -= N1;
  if (idx < N2) { Wb2[idx] = f2bf(wb2[idx]); return; }
  idx -= N2;
  if (idx < N3) {
    unsigned c = idx >> 10, k = idx & 1023u;
    unsigned i = c / 3u, hd = c % 3u;
    float v = (hd == 0u) ? wff1[i * 1024u + k]
            : (hd == 1u) ? wff2[i * 1024u + k]
                         : (wta[i * 1024u + k] + wtb[i * 1024u + k]);
    Whd[idx] = f2bf(v);
    return;
  }
  idx -= N3;
  if (idx < NH) { Hbuf[idx] = 0; return; }
  idx -= NH;
  if (idx < NF) { flags[idx] = 0u; }
}

// ---- persistent recurrent kernel ----
__global__ __launch_bounds__(256, 1) void cfc_run(
    const float* __restrict__ x,
    const float* __restrict__ bb1, const float* __restrict__ bb2,
    const float* __restrict__ bff1, const float* __restrict__ bff2,
    const float* __restrict__ bta, const float* __restrict__ btb,
    unsigned char* __restrict__ ws, float* __restrict__ out) {
  extern __shared__ char smem[];
  __shared__ int sh_rank;
  __shared__ volatile unsigned sh_epoch;
  const int tid = threadIdx.x;         // 0..255
  const int w = tid >> 6;              // wave 0..3
  const int lane = tid & 63;

  // --- self-organize by physical die ---
  unsigned xcc;
  asm volatile("s_getreg_b32 %0, hwreg(HW_REG_XCC_ID)" : "=s"(xcc));
  xcc &= 7u;
  unsigned* pools = (unsigned*)(ws + OFF_POOL);
  if (tid == 0) {
    sh_rank = (int)atomicAdd(pools + xcc, 1u);
    sh_epoch = 0u;
  }
  __syncthreads();
  const int r = sh_rank & 31;          // rank within XCD: 0..31

  const short* Wb1 = (const short*)(ws + OFF_WB1);
  const short* Wb2 = (const short*)(ws + OFF_WB2);
  const short* Whd = (const short*)(ws + OFF_WHD);
  char* z1_x = (char*)(ws + OFF_Z1) + (xcc << 14);   // [8][1024] bf16
  char* z2_x = (char*)(ws + OFF_Z2) + (xcc << 14);
  char* h_x  = (char*)(ws + OFF_H)  + (xcc << 13);   // [8][512] bf16
  unsigned* cnt = (unsigned*)(ws + OFF_FLAGS + (xcc << 9));  // 1 ctr / XCD

  const int m0 = (int)xcc << 3;        // 8 batch rows per XCD
  const int n0 = r << 5;               // 32 output cols (S1/S2)
  const int ib = r << 4;               // 16 output i's (S3)

  const int row16 = lane & 15;         // A-row / B-col index of this lane
  const int row8 = row16 & 7;          // real batch row within XCD (M=8)
  const int kg = lane >> 4;            // k-group 0..3 (8 bf16 each)
  const int kg16 = kg << 4;
  const int swzm = (row16 & 7) << 4;   // LDS row xor-swizzle
  const int tw = w >> 1, hw = w & 1;   // S1/S2 job: (tile, K-half)

  // ---- one-time LDS preload: Wb1/Wb2 32-row slices (xor-swizzled) ----
  for (int c = tid; c < 32 * 96; c += 256) {
    int rr = c / 96, kb = (c % 96) << 4;
    *(bf16x8*)(smem + SM_WB1 + rr * 1536 + (kb ^ ((rr & 7) << 4))) =
        *(const bf16x8*)(Wb1 + (size_t)(n0 + rr) * 768 + (kb >> 1));
  }
  for (int c = tid; c < 32 * 128; c += 256) {
    int rr = c >> 7, kb = (c & 127) << 4;
    *(bf16x8*)(smem + SM_WB2 + rr * 2048 + (kb ^ ((rr & 7) << 4))) =
        *(const bf16x8*)(Wb2 + (size_t)(n0 + rr) * 1024 + (kb >> 1));
  }

  // ---- one-time Whd slice into VGPRs (waves 0..2; 128 VGPR) ----
  bf16x8 whd[32];
  if (w < 3) {
    const short* wp = Whd + (size_t)(r * 48 + w * 16 + row16) * 1024 + kg * 8;
#pragma unroll
    for (int kc = 0; kc < 32; ++kc) whd[kc] = *(const bf16x8*)(wp + kc * 32);
  }

  float* SAf = (float*)(smem + SM_SA);
  float* XAf = (float*)(smem + SM_XA);

  // epilogue constants
  const int et = tid >> 7, err = (tid >> 4) & 7, ecc = tid & 15;
  const int elane = ((err >> 2) << 4) + ecc, ei = err & 3;
  const float b1e = bb1[n0 + et * 16 + ecc];
  const float b2e = bb2[n0 + et * 16 + ecc];
  const int rr3 = tid >> 4, il3 = tid & 15;    // S3 epilogue (tid<128)
  float bf1e = 0.f, bf2e = 0.f, btabe = 0.f;
  if (tid < 128) {
    bf1e = bff1[ib + il3];
    bf2e = bff2[ib + il3];
    btabe = bta[ib + il3] + btb[ib + il3];
  }

  // x-part of S1 for step tn (wave 3 only): acc into XA
  auto xpart = [&](int tn) {
    const float* xr = x + (size_t)(m0 + row8) * (Tt * Ii) + (size_t)tn * Ii;
    bf16x8 a[8];
#pragma unroll
    for (int kc = 0; kc < 8; ++kc) {
      const f32x4 va = *(const f32x4*)(xr + kc * 32 + kg * 8);
      const f32x4 vb = *(const f32x4*)(xr + kc * 32 + kg * 8 + 4);
#pragma unroll
      for (int j = 0; j < 4; ++j) { a[kc][j] = f2bf(va[j]); a[kc][4 + j] = f2bf(vb[j]); }
    }
    f32x4 q00 = {0.f,0.f,0.f,0.f}, q01 = {0.f,0.f,0.f,0.f};
    f32x4 q10 = {0.f,0.f,0.f,0.f}, q11 = {0.f,0.f,0.f,0.f};
#pragma unroll
    for (int kc = 0; kc < 8; ++kc) {
      const bf16x8 b0 = *(const bf16x8*)(smem + SM_WB1 + row16 * 1536 + (((kc << 6) + kg16) ^ swzm));
      const bf16x8 b1 = *(const bf16x8*)(smem + SM_WB1 + (16 + row16) * 1536 + (((kc << 6) + kg16) ^ swzm));
      if (kc & 1) {
        q01 = __builtin_amdgcn_mfma_f32_16x16x32_bf16(a[kc], b0, q01, 0, 0, 0);
        q11 = __builtin_amdgcn_mfma_f32_16x16x32_bf16(a[kc], b1, q11, 0, 0, 0);
      } else {
        q00 = __builtin_amdgcn_mfma_f32_16x16x32_bf16(a[kc], b0, q00, 0, 0, 0);
        q10 = __builtin_amdgcn_mfma_f32_16x16x32_bf16(a[kc], b1, q10, 0, 0, 0);
      }
    }
    *(f32x4*)(XAf + 0 * 256 + lane * 4) = q00 + q01;
    *(f32x4*)(XAf + 1 * 256 + lane * 4) = q10 + q11;
  };

  __syncthreads();                 // LDS weights ready
  if (w == 3) xpart(0);
  __syncthreads();                 // XA(0) ready

#pragma unroll 1
  for (int t = 0; t < Tt; ++t) {
    const unsigned g1 = 3u * t + 1u, g2 = 3u * t + 2u, g3 = 3u * t + 3u;
    if (t) bar_wait(cnt, tid, 32u * (3u * t), &sh_epoch);  // h(t-1) visible

    // ===== S1: z1 = lecun(cat(x_t,h) @ Wb1^T + bb1); h-part K-split =====
    {
      f32x4 acc0, acc1 = {0.f,0.f,0.f,0.f};
      if (hw == 0) acc0 = *(const f32x4*)(XAf + tw * 256 + lane * 4);
      else         acc0 = f32x4{0.f,0.f,0.f,0.f};
      bf16x8 ha[8];
      burst8(h_x + (row8 << 10) + (kg << 4) + (hw << 9), ha);
#pragma unroll
      for (int k = 0; k < 8; ++k) {
        const int kc = 8 + hw * 8 + k;
        const bf16x8 b = *(const bf16x8*)(smem + SM_WB1 + (tw * 16 + row16) * 1536 + (((kc << 6) + kg16) ^ swzm));
        if (k & 1) acc1 = __builtin_amdgcn_mfma_f32_16x16x32_bf16(ha[k], b, acc1, 0, 0, 0);
        else       acc0 = __builtin_amdgcn_mfma_f32_16x16x32_bf16(ha[k], b, acc0, 0, 0, 0);
      }
      const f32x4 asum = acc0 + acc1;
      *(f32x4*)(SAf + (tw * 2 + hw) * 256 + lane * 4) = asum;
      __syncthreads();
      const float v = SAf[(et * 2 + 0) * 256 + elane * 4 + ei] +
                      SAf[(et * 2 + 1) * 256 + elane * 4 + ei] + b1e;
      st2f(z1_x + err * 2048 + ((n0 + et * 16 + ecc) << 1), f2bf(lecun_act(v)));
    }
    bar_arrive(cnt, tid);
    bar_wait(cnt, tid, 32u * g1, &sh_epoch);

    // ===== S2: z2 = lecun(z1 @ Wb2^T + bb2); K-split =====
    {
      bf16x8 zb[16];
      burst16(z1_x + (row8 << 11) + (kg << 4) + (hw << 10), zb);
      f32x4 acc0 = {0.f,0.f,0.f,0.f}, acc1 = {0.f,0.f,0.f,0.f};
#pragma unroll
      for (int k = 0; k < 16; ++k) {
        const int kc = hw * 16 + k;
        const bf16x8 b = *(const bf16x8*)(smem + SM_WB2 + (tw * 16 + row16) * 2048 + (((kc << 6) + kg16) ^ swzm));
        if (k & 1) acc1 = __builtin_amdgcn_mfma_f32_16x16x32_bf16(zb[k], b, acc1, 0, 0, 0);
        else       acc0 = __builtin_amdgcn_mfma_f32_16x16x32_bf16(zb[k], b, acc0, 0, 0, 0);
      }
      const f32x4 asum = acc0 + acc1;
      __syncthreads();   // WAR: SA read at end of S1 epilogue
      *(f32x4*)(SAf + (tw * 2 + hw) * 256 + lane * 4) = asum;
      __syncthreads();
      const float v = SAf[(et * 2 + 0) * 256 + elane * 4 + ei] +
                      SAf[(et * 2 + 1) * 256 + elane * 4 + ei] + b2e;
      st2f(z2_x + err * 2048 + ((n0 + et * 16 + ecc) << 1), f2bf(lecun_act(v)));
    }
    bar_arrive(cnt, tid);

    // ===== S3: heads (waves 0-2) ; wave 3: xpart(t+1) =====
    if (w < 3) {
      bar_wait(cnt, tid, 32u * g2, &sh_epoch);
      f32x4 p0 = {0.f,0.f,0.f,0.f}, p1 = {0.f,0.f,0.f,0.f};
      bf16x8 za[16];
      burst16(z2_x + (row8 << 11) + (kg << 4), za);
#pragma unroll
      for (int k = 0; k < 16; ++k) {
        if (k & 1) p1 = __builtin_amdgcn_mfma_f32_16x16x32_bf16(za[k], whd[k], p1, 0, 0, 0);
        else       p0 = __builtin_amdgcn_mfma_f32_16x16x32_bf16(za[k], whd[k], p0, 0, 0, 0);
      }
      burst16(z2_x + (row8 << 11) + (kg << 4) + 1024, za);
#pragma unroll
      for (int k = 0; k < 16; ++k) {
        if (k & 1) p1 = __builtin_amdgcn_mfma_f32_16x16x32_bf16(za[k], whd[16 + k], p1, 0, 0, 0);
        else       p0 = __builtin_amdgcn_mfma_f32_16x16x32_bf16(za[k], whd[16 + k], p0, 0, 0, 0);
      }
      *(f32x4*)(SAf + w * 256 + lane * 4) = p0 + p1;   // S3D shares SA region
    } else {
      if (t + 1 < Tt) xpart(t + 1);
    }
    __syncthreads();
    if (tid < 128) {
      float d[3];
#pragma unroll
      for (int hd = 0; hd < 3; ++hd) {
        const int hc = 3 * il3 + hd;
        d[hd] = SAf[(hc >> 4) * 256 + ((((rr3 >> 2) << 4) + (hc & 15)) << 2) + (rr3 & 3)];
      }
      const float ff1 = fast_tanh(d[0] + bf1e);
      const float ff2 = fast_tanh(d[1] + bf2e);
      const float tt  = fast_sig(d[2] + btabe);
      const float hn = ff1 + tt * (ff2 - ff1);
      st2f(h_x + (rr3 << 10) + ((ib + il3) << 1), f2bf(hn));
      out[(size_t)(m0 + rr3) * (Tt * Hh) + (size_t)t * Hh + ib + il3] = hn;
    }
    bar_arrive(cnt, tid);
  }
}

extern "C" void kernel_launch(void* const* d_in, const int* in_sizes, int n_in,
                              void* d_out, int out_size, void* d_ws, size_t ws_size,
                              hipStream_t stream) {
  const float* x    = (const float*)d_in[0];
  const float* wb1  = (const float*)d_in[1];
  const float* bb1  = (const float*)d_in[2];
  const float* wb2  = (const float*)d_in[3];
  const float* bb2  = (const float*)d_in[4];
  const float* wff1 = (const float*)d_in[5];
  const float* bff1 = (const float*)d_in[6];
  const float* wff2 = (const float*)d_in[7];
  const float* bff2 = (const float*)d_in[8];
  const float* wta  = (const float*)d_in[9];
  const float* bta  = (const float*)d_in[10];
  const float* wtb  = (const float*)d_in[11];
  const float* btb  = (const float*)d_in[12];
  unsigned char* ws = (unsigned char*)d_ws;

  const unsigned prep_items = 786432u + 1048576u + 1572864u + 32768u + 1040u;
  cfc_prep<<<(prep_items + 255u) / 256u, 256, 0, stream>>>(wb1, wb2, wff1, wff2, wta, wtb, ws);
  cfc_run<<<256, 256, SM_TOTAL, stream>>>(x, bb1, bb2, bff1, bff2, bta, btb, ws, (float*)d_out);
}

// Round 16
// 6286.903 us; speedup vs baseline: 1.1107x; 1.1107x over previous
//
#include <hip/hip_runtime.h>
#include <hip/hip_bf16.h>

// CfC recurrent net. B=64,T=512,I=256,H=512,BU=1024.
// FINAL (revert to R11 — best of 7 sync designs, 6.30ms):
// Persistent kernel, 256 wgs x 256 threads; batch partitioned over XCDs
// (8 XCDs x 8 rows, HW_REG_XCC_ID self-organization); weights LDS/VGPR-
// resident; activations circulate in each XCD's L2 (sc0 bursts + post-
// barrier buffer_inv); barrier = non-returning far atomic arrive + tid0
// system-scope load-poll + LDS fanout. Remaining time = 512 steps x 3
// cross-CU visibility handoffs (~3.3us each, invariant across R9-R15's
// seven structurally different implementations) — latency floor.

#define Tt  512
#define Ii  256
#define Hh  512
#define BUu 1024

typedef __attribute__((ext_vector_type(8))) short bf16x8;   // 8 bf16 = 4 VGPR
typedef __attribute__((ext_vector_type(4))) float f32x4;

// ---- workspace layout (bytes) ----
#define OFF_WB1   0u         // bf16 [1024][768]
#define OFF_WB2   1572864u   // bf16 [1024][1024]
#define OFF_WHD   3670016u   // bf16 [1536][1024], row c=3*i+head (head2=wta+wtb)
#define OFF_Z1    6815744u   // bf16 [8 xcd][8][1024]  (16 KB per XCD)
#define OFF_Z2    6946816u   // bf16 [8 xcd][8][1024]
#define OFF_H     7077888u   // bf16 [8 xcd][8][512]   (8 KB per XCD)
#define OFF_FLAGS 7143424u   // per-XCD arrival counter @ 512B stride (4 KB)
#define OFF_POOL  7147520u   // uint[16] rank pools

// ---- LDS layout (dynamic) ----
#define SM_WB1 0         // 32 rows x 1536 B (K=768)
#define SM_WB2 49152     // 32 rows x 2048 B (K=1024)
#define SM_SA  114688    // 4 KB stage: S1/S2 [2][2][64][4]f32, S3 [3][64][4]f32
#define SM_XA  118784    // 2 KB: xpart acc [2][64][4] f32
#define SM_TOTAL 120832

__device__ __forceinline__ short f2bf(float f) {   // fp32 -> bf16 RNE
  unsigned u = __builtin_bit_cast(unsigned, f);
  u += 0x7FFFu + ((u >> 16) & 1u);
  return (short)(u >> 16);
}
__device__ __forceinline__ float fast_tanh(float u) {
  float e = __expf(2.0f * u);
  return (e - 1.0f) / (e + 1.0f);
}
__device__ __forceinline__ float fast_sig(float x) {
  return 1.0f / (1.0f + __expf(-x));
}
__device__ __forceinline__ float lecun_act(float u) {
  return 1.7159f * fast_tanh(0.666f * u);
}

// ---- XCD-local transport (R7/R9/R11-proven) ----
__device__ __forceinline__ void burst8(const void* p, bf16x8* v) {
  asm volatile(
      "global_load_dwordx4 %0, %8, off sc0\n\t"
      "global_load_dwordx4 %1, %8, off offset:64 sc0\n\t"
      "global_load_dwordx4 %2, %8, off offset:128 sc0\n\t"
      "global_load_dwordx4 %3, %8, off offset:192 sc0\n\t"
      "global_load_dwordx4 %4, %8, off offset:256 sc0\n\t"
      "global_load_dwordx4 %5, %8, off offset:320 sc0\n\t"
      "global_load_dwordx4 %6, %8, off offset:384 sc0\n\t"
      "global_load_dwordx4 %7, %8, off offset:448 sc0\n\t"
      "s_waitcnt vmcnt(0)"
      : "=&v"(v[0]), "=&v"(v[1]), "=&v"(v[2]), "=&v"(v[3]),
        "=&v"(v[4]), "=&v"(v[5]), "=&v"(v[6]), "=&v"(v[7])
      : "v"(p));
}
__device__ __forceinline__ void burst16(const void* p, bf16x8* v) {
  asm volatile(
      "global_load_dwordx4 %0, %16, off sc0\n\t"
      "global_load_dwordx4 %1, %16, off offset:64 sc0\n\t"
      "global_load_dwordx4 %2, %16, off offset:128 sc0\n\t"
      "global_load_dwordx4 %3, %16, off offset:192 sc0\n\t"
      "global_load_dwordx4 %4, %16, off offset:256 sc0\n\t"
      "global_load_dwordx4 %5, %16, off offset:320 sc0\n\t"
      "global_load_dwordx4 %6, %16, off offset:384 sc0\n\t"
      "global_load_dwordx4 %7, %16, off offset:448 sc0\n\t"
      "global_load_dwordx4 %8, %16, off offset:512 sc0\n\t"
      "global_load_dwordx4 %9, %16, off offset:576 sc0\n\t"
      "global_load_dwordx4 %10, %16, off offset:640 sc0\n\t"
      "global_load_dwordx4 %11, %16, off offset:704 sc0\n\t"
      "global_load_dwordx4 %12, %16, off offset:768 sc0\n\t"
      "global_load_dwordx4 %13, %16, off offset:832 sc0\n\t"
      "global_load_dwordx4 %14, %16, off offset:896 sc0\n\t"
      "global_load_dwordx4 %15, %16, off offset:960 sc0\n\t"
      "s_waitcnt vmcnt(0)"
      : "=&v"(v[0]), "=&v"(v[1]), "=&v"(v[2]), "=&v"(v[3]),
        "=&v"(v[4]), "=&v"(v[5]), "=&v"(v[6]), "=&v"(v[7]),
        "=&v"(v[8]), "=&v"(v[9]), "=&v"(v[10]), "=&v"(v[11]),
        "=&v"(v[12]), "=&v"(v[13]), "=&v"(v[14]), "=&v"(v[15])
      : "v"(p));
}
// flag observation: system-scope load (bypass L1+L2, reads the chip
// coherence point where the arrive-atomics execute). R11-proven.
__device__ __forceinline__ unsigned ldpoll(const unsigned* p) {
  unsigned r;
  asm volatile("global_load_dword %0, %1, off sc0 sc1\n\ts_waitcnt vmcnt(0)"
               : "=&v"(r) : "v"(p) : "memory");
  return r;
}
__device__ __forceinline__ void inv_l1() {
  asm volatile("buffer_inv sc0\n\ts_waitcnt vmcnt(0)" ::: "memory");
}

// arrive: syncthreads drains all waves' stores into L2, then ONE +1 by tid0.
__device__ __forceinline__ void bar_arrive(unsigned* cnt, int tid) {
  __syncthreads();
  if (tid == 0)
    asm volatile("global_atomic_add %0, %1, off" :: "v"(cnt), "v"(1u) : "memory");
}
// wait: tid0 load-polls the counter until >= target, publishes to LDS; all
// threads spin on LDS; then EVERY wave invalidates L1 before its data bursts.
__device__ __forceinline__ void bar_wait(unsigned* cnt, int tid, unsigned target,
                                         volatile unsigned* eph) {
  if (tid == 0) {
    for (int spin = 0; spin < (1 << 17); ++spin) {
      if (ldpoll(cnt) >= target) break;
      __builtin_amdgcn_s_sleep(1);
    }
    *eph = target;    // release the wg (LDS)
  }
  while (*eph < target) __builtin_amdgcn_s_sleep(1);
  inv_l1();           // per-wave: fresh L2 reads for the bursts that follow
}

// ---- prep: weight conversion, fused head matrix, zero h/counters/pools ----
__global__ void cfc_prep(const float* __restrict__ wb1, const float* __restrict__ wb2,
                         const float* __restrict__ wff1, const float* __restrict__ wff2,
                         const float* __restrict__ wta, const float* __restrict__ wtb,
                         unsigned char* __restrict__ ws) {
  const unsigned N1 = 1024u * 768u;
  const unsigned N2 = 1024u * 1024u;
  const unsigned N3 = 1536u * 1024u;
  const unsigned NH = 32768u;          // h shorts (8 XCD x 8 x 512)
  const unsigned NF = 1040u;           // counter region 4KB + pools 64B dwords
  unsigned idx = blockIdx.x * blockDim.x + threadIdx.x;
  short* Wb1 = (short*)(ws + OFF_WB1);
  short* Wb2 = (short*)(ws + OFF_WB2);
  short* Whd = (short*)(ws + OFF_WHD);
  short* Hbuf = (short*)(ws + OFF_H);
  unsigned* flags = (unsigned*)(ws + OFF_FLAGS);
  if (idx < N1) { Wb1[idx] = f2bf(wb1[idx]); return; }
  idx -= N1;
  if (idx < N2) { Wb2[idx] = f2bf(wb2[idx]); return; }
  idx -= N2;
  if (idx < N3) {
    unsigned c = idx >> 10, k = idx & 1023u;
    unsigned i = c / 3u, hd = c % 3u;
    float v = (hd == 0u) ? wff1[i * 1024u + k]
            : (hd == 1u) ? wff2[i * 1024u + k]
                         : (wta[i * 1024u + k] + wtb[i * 1024u + k]);
    Whd[idx] = f2bf(v);
    return;
  }
  idx -= N3;
  if (idx < NH) { Hbuf[idx] = 0; return; }
  idx -= NH;
  if (idx < NF) { flags[idx] = 0u; }
}

// ---- persistent recurrent kernel ----
__global__ __launch_bounds__(256, 1) void cfc_run(
    const float* __restrict__ x,
    const float* __restrict__ bb1, const float* __restrict__ bb2,
    const float* __restrict__ bff1, const float* __restrict__ bff2,
    const float* __restrict__ bta, const float* __restrict__ btb,
    unsigned char* __restrict__ ws, float* __restrict__ out) {
  extern __shared__ char smem[];
  __shared__ int sh_rank;
  __shared__ volatile unsigned sh_epoch;
  const int tid = threadIdx.x;         // 0..255
  const int w = tid >> 6;              // wave 0..3
  const int lane = tid & 63;

  // --- self-organize by physical die ---
  unsigned xcc;
  asm volatile("s_getreg_b32 %0, hwreg(HW_REG_XCC_ID)" : "=s"(xcc));
  xcc &= 7u;
  unsigned* pools = (unsigned*)(ws + OFF_POOL);
  if (tid == 0) {
    sh_rank = (int)atomicAdd(pools + xcc, 1u);
    sh_epoch = 0u;
  }
  __syncthreads();
  const int r = sh_rank & 31;          // rank within XCD: 0..31

  const short* Wb1 = (const short*)(ws + OFF_WB1);
  const short* Wb2 = (const short*)(ws + OFF_WB2);
  const short* Whd = (const short*)(ws + OFF_WHD);
  char* z1_x = (char*)(ws + OFF_Z1) + (xcc << 14);   // [8][1024] bf16
  char* z2_x = (char*)(ws + OFF_Z2) + (xcc << 14);
  char* h_x  = (char*)(ws + OFF_H)  + (xcc << 13);   // [8][512] bf16
  unsigned* cnt = (unsigned*)(ws + OFF_FLAGS + (xcc << 9));  // 1 ctr / XCD

  const int m0 = (int)xcc << 3;        // 8 batch rows per XCD
  const int n0 = r << 5;               // 32 output cols (S1/S2)
  const int ib = r << 4;               // 16 output i's (S3)

  const int row16 = lane & 15;         // A-row / B-col index of this lane
  const int row8 = row16 & 7;          // real batch row within XCD (M=8)
  const int kg = lane >> 4;            // k-group 0..3 (8 bf16 each)
  const int kg16 = kg << 4;
  const int swzm = (row16 & 7) << 4;   // LDS row xor-swizzle
  const int tw = w >> 1, hw = w & 1;   // S1/S2 job: (tile, K-half)

  // ---- one-time LDS preload: Wb1/Wb2 32-row slices (xor-swizzled) ----
  for (int c = tid; c < 32 * 96; c += 256) {
    int rr = c / 96, kb = (c % 96) << 4;
    *(bf16x8*)(smem + SM_WB1 + rr * 1536 + (kb ^ ((rr & 7) << 4))) =
        *(const bf16x8*)(Wb1 + (size_t)(n0 + rr) * 768 + (kb >> 1));
  }
  for (int c = tid; c < 32 * 128; c += 256) {
    int rr = c >> 7, kb = (c & 127) << 4;
    *(bf16x8*)(smem + SM_WB2 + rr * 2048 + (kb ^ ((rr & 7) << 4))) =
        *(const bf16x8*)(Wb2 + (size_t)(n0 + rr) * 1024 + (kb >> 1));
  }

  // ---- one-time Whd slice into VGPRs (waves 0..2; 128 VGPR) ----
  bf16x8 whd[32];
  if (w < 3) {
    const short* wp = Whd + (size_t)(r * 48 + w * 16 + row16) * 1024 + kg * 8;
#pragma unroll
    for (int kc = 0; kc < 32; ++kc) whd[kc] = *(const bf16x8*)(wp + kc * 32);
  }

  float* SAf = (float*)(smem + SM_SA);
  float* XAf = (float*)(smem + SM_XA);

  // epilogue constants
  const int et = tid >> 7, err = (tid >> 4) & 7, ecc = tid & 15;
  const int elane = ((err >> 2) << 4) + ecc, ei = err & 3;
  const float b1e = bb1[n0 + et * 16 + ecc];
  const float b2e = bb2[n0 + et * 16 + ecc];
  const int rr3 = tid >> 4, il3 = tid & 15;    // S3 epilogue (tid<128)
  float bf1e = 0.f, bf2e = 0.f, btabe = 0.f;
  if (tid < 128) {
    bf1e = bff1[ib + il3];
    bf2e = bff2[ib + il3];
    btabe = bta[ib + il3] + btb[ib + il3];
  }

  // x-part of S1 for step tn (wave 3 only): acc into XA
  auto xpart = [&](int tn) {
    const float* xr = x + (size_t)(m0 + row8) * (Tt * Ii) + (size_t)tn * Ii;
    bf16x8 a[8];
#pragma unroll
    for (int kc = 0; kc < 8; ++kc) {
      const f32x4 va = *(const f32x4*)(xr + kc * 32 + kg * 8);
      const f32x4 vb = *(const f32x4*)(xr + kc * 32 + kg * 8 + 4);
#pragma unroll
      for (int j = 0; j < 4; ++j) { a[kc][j] = f2bf(va[j]); a[kc][4 + j] = f2bf(vb[j]); }
    }
    f32x4 q00 = {0.f,0.f,0.f,0.f}, q01 = {0.f,0.f,0.f,0.f};
    f32x4 q10 = {0.f,0.f,0.f,0.f}, q11 = {0.f,0.f,0.f,0.f};
#pragma unroll
    for (int kc = 0; kc < 8; ++kc) {
      const bf16x8 b0 = *(const bf16x8*)(smem + SM_WB1 + row16 * 1536 + (((kc << 6) + kg16) ^ swzm));
      const bf16x8 b1 = *(const bf16x8*)(smem + SM_WB1 + (16 + row16) * 1536 + (((kc << 6) + kg16) ^ swzm));
      if (kc & 1) {
        q01 = __builtin_amdgcn_mfma_f32_16x16x32_bf16(a[kc], b0, q01, 0, 0, 0);
        q11 = __builtin_amdgcn_mfma_f32_16x16x32_bf16(a[kc], b1, q11, 0, 0, 0);
      } else {
        q00 = __builtin_amdgcn_mfma_f32_16x16x32_bf16(a[kc], b0, q00, 0, 0, 0);
        q10 = __builtin_amdgcn_mfma_f32_16x16x32_bf16(a[kc], b1, q10, 0, 0, 0);
      }
    }
    *(f32x4*)(XAf + 0 * 256 + lane * 4) = q00 + q01;
    *(f32x4*)(XAf + 1 * 256 + lane * 4) = q10 + q11;
  };

  __syncthreads();                 // LDS weights ready
  if (w == 3) xpart(0);
  __syncthreads();                 // XA(0) ready

#pragma unroll 1
  for (int t = 0; t < Tt; ++t) {
    const unsigned g1 = 3u * t + 1u, g2 = 3u * t + 2u, g3 = 3u * t + 3u;
    if (t) bar_wait(cnt, tid, 32u * (3u * t), &sh_epoch);  // h(t-1) in our L2

    // ===== S1: z1 = lecun(cat(x_t,h) @ Wb1^T + bb1); h-part K-split =====
    {
      f32x4 acc0, acc1 = {0.f,0.f,0.f,0.f};
      if (hw == 0) acc0 = *(const f32x4*)(XAf + tw * 256 + lane * 4);
      else         acc0 = f32x4{0.f,0.f,0.f,0.f};
      bf16x8 ha[8];
      burst8(h_x + (row8 << 10) + (kg << 4) + (hw << 9), ha);
#pragma unroll
      for (int k = 0; k < 8; ++k) {
        const int kc = 8 + hw * 8 + k;
        const bf16x8 b = *(const bf16x8*)(smem + SM_WB1 + (tw * 16 + row16) * 1536 + (((kc << 6) + kg16) ^ swzm));
        if (k & 1) acc1 = __builtin_amdgcn_mfma_f32_16x16x32_bf16(ha[k], b, acc1, 0, 0, 0);
        else       acc0 = __builtin_amdgcn_mfma_f32_16x16x32_bf16(ha[k], b, acc0, 0, 0, 0);
      }
      const f32x4 asum = acc0 + acc1;
      *(f32x4*)(SAf + (tw * 2 + hw) * 256 + lane * 4) = asum;
      __syncthreads();
      const float v = SAf[(et * 2 + 0) * 256 + elane * 4 + ei] +
                      SAf[(et * 2 + 1) * 256 + elane * 4 + ei] + b1e;
      *(short*)(z1_x + err * 2048 + ((n0 + et * 16 + ecc) << 1)) = f2bf(lecun_act(v));
    }
    bar_arrive(cnt, tid);
    bar_wait(cnt, tid, 32u * g1, &sh_epoch);

    // ===== S2: z2 = lecun(z1 @ Wb2^T + bb2); K-split =====
    {
      bf16x8 zb[16];
      burst16(z1_x + (row8 << 11) + (kg << 4) + (hw << 10), zb);
      f32x4 acc0 = {0.f,0.f,0.f,0.f}, acc1 = {0.f,0.f,0.f,0.f};
#pragma unroll
      for (int k = 0; k < 16; ++k) {
        const int kc = hw * 16 + k;
        const bf16x8 b = *(const bf16x8*)(smem + SM_WB2 + (tw * 16 + row16) * 2048 + (((kc << 6) + kg16) ^ swzm));
        if (k & 1) acc1 = __builtin_amdgcn_mfma_f32_16x16x32_bf16(zb[k], b, acc1, 0, 0, 0);
        else       acc0 = __builtin_amdgcn_mfma_f32_16x16x32_bf16(zb[k], b, acc0, 0, 0, 0);
      }
      const f32x4 asum = acc0 + acc1;
      __syncthreads();   // WAR: SA read at end of S1 epilogue
      *(f32x4*)(SAf + (tw * 2 + hw) * 256 + lane * 4) = asum;
      __syncthreads();
      const float v = SAf[(et * 2 + 0) * 256 + elane * 4 + ei] +
                      SAf[(et * 2 + 1) * 256 + elane * 4 + ei] + b2e;
      *(short*)(z2_x + err * 2048 + ((n0 + et * 16 + ecc) << 1)) = f2bf(lecun_act(v));
    }
    bar_arrive(cnt, tid);

    // ===== S3: heads (waves 0-2) ; wave 3: xpart(t+1) =====
    if (w < 3) {
      bar_wait(cnt, tid, 32u * g2, &sh_epoch);
      f32x4 p0 = {0.f,0.f,0.f,0.f}, p1 = {0.f,0.f,0.f,0.f};
      bf16x8 za[16];
      burst16(z2_x + (row8 << 11) + (kg << 4), za);
#pragma unroll
      for (int k = 0; k < 16; ++k) {
        if (k & 1) p1 = __builtin_amdgcn_mfma_f32_16x16x32_bf16(za[k], whd[k], p1, 0, 0, 0);
        else       p0 = __builtin_amdgcn_mfma_f32_16x16x32_bf16(za[k], whd[k], p0, 0, 0, 0);
      }
      burst16(z2_x + (row8 << 11) + (kg << 4) + 1024, za);
#pragma unroll
      for (int k = 0; k < 16; ++k) {
        if (k & 1) p1 = __builtin_amdgcn_mfma_f32_16x16x32_bf16(za[k], whd[16 + k], p1, 0, 0, 0);
        else       p0 = __builtin_amdgcn_mfma_f32_16x16x32_bf16(za[k], whd[16 + k], p0, 0, 0, 0);
      }
      *(f32x4*)(SAf + w * 256 + lane * 4) = p0 + p1;   // S3D shares SA region
    } else {
      if (t + 1 < Tt) xpart(t + 1);
    }
    __syncthreads();
    if (tid < 128) {
      float d[3];
#pragma unroll
      for (int hd = 0; hd < 3; ++hd) {
        const int hc = 3 * il3 + hd;
        d[hd] = SAf[(hc >> 4) * 256 + ((((rr3 >> 2) << 4) + (hc & 15)) << 2) + (rr3 & 3)];
      }
      const float ff1 = fast_tanh(d[0] + bf1e);
      const float ff2 = fast_tanh(d[1] + bf2e);
      const float tt  = fast_sig(d[2] + btabe);
      const float hn = ff1 + tt * (ff2 - ff1);
      *(short*)(h_x + (rr3 << 10) + ((ib + il3) << 1)) = f2bf(hn);
      out[(size_t)(m0 + rr3) * (Tt * Hh) + (size_t)t * Hh + ib + il3] = hn;
    }
    bar_arrive(cnt, tid);
  }
}

extern "C" void kernel_launch(void* const* d_in, const int* in_sizes, int n_in,
                              void* d_out, int out_size, void* d_ws, size_t ws_size,
                              hipStream_t stream) {
  const float* x    = (const float*)d_in[0];
  const float* wb1  = (const float*)d_in[1];
  const float* bb1  = (const float*)d_in[2];
  const float* wb2  = (const float*)d_in[3];
  const float* bb2  = (const float*)d_in[4];
  const float* wff1 = (const float*)d_in[5];
  const float* bff1 = (const float*)d_in[6];
  const float* wff2 = (const float*)d_in[7];
  const float* bff2 = (const float*)d_in[8];
  const float* wta  = (const float*)d_in[9];
  const float* bta  = (const float*)d_in[10];
  const float* wtb  = (const float*)d_in[11];
  const float* btb  = (const float*)d_in[12];
  unsigned char* ws = (unsigned char*)d_ws;

  const unsigned prep_items = 786432u + 1048576u + 1572864u + 32768u + 1040u;
  cfc_prep<<<(prep_items + 255u) / 256u, 256, 0, stream>>>(wb1, wb2, wff1, wff2, wta, wtb, ws);
  cfc_run<<<256, 256, SM_TOTAL, stream>>>(x, bb1, bb2, bff1, bff2, bta, btb, ws, (float*)d_out);
}